// Round 1
// baseline (502.833 us; speedup 1.0000x reference)
//
#include <hip/hip_runtime.h>

typedef unsigned short u16;
typedef __bf16 bf16x8 __attribute__((ext_vector_type(8)));
typedef float f32x4 __attribute__((ext_vector_type(4)));

__device__ __forceinline__ u16 f2bf(float f) {
  unsigned int u = __builtin_bit_cast(unsigned int, f);
  u += 0x7fffu + ((u >> 16) & 1u);
  return (u16)(u >> 16);
}
__device__ __forceinline__ float bf2f(u16 h) {
  unsigned int u = ((unsigned int)h) << 16;
  return __builtin_bit_cast(float, u);
}

// ---------------------------------------------------------------------------
// k_prep: convert weights fp32 -> bf16, swizzled into MFMA B-fragment order.
// Fragment task (ks, nt, lane): 8 elements W[ks*32 + (lane>>4)*8 + j][nt*16 + (lane&15)]
// stored contiguously at dst[((ks*16+nt)*64 + lane)*8 + j].
// W1: 12 ksteps (K=384). W2/R1/R2/R3: 8 ksteps (K=256). All have 16 ntiles (ncols=256).
// ---------------------------------------------------------------------------
__global__ __launch_bounds__(256) void k_prep(
    const float* __restrict__ W1, const float* __restrict__ W2,
    const float* __restrict__ R1, const float* __restrict__ R2, const float* __restrict__ R3,
    u16* __restrict__ W1s, u16* __restrict__ W2s,
    u16* __restrict__ R1s, u16* __restrict__ R2s, u16* __restrict__ R3s) {
  int t = blockIdx.x * 256 + threadIdx.x;
  const float* src; u16* dst; int lt;
  if (t < 12288) { src = W1; dst = W1s; lt = t; }
  else {
    int u = t - 12288;
    int m = u >> 13;
    lt = u & 8191;
    if (m == 0)      { src = W2; dst = W2s; }
    else if (m == 1) { src = R1; dst = R1s; }
    else if (m == 2) { src = R2; dst = R2s; }
    else if (m == 3) { src = R3; dst = R3s; }
    else return;
  }
  int lane = lt & 63;
  int nt = (lt >> 6) & 15;
  int ks = lt >> 10;
  int col = nt * 16 + (lane & 15);
  int kb = ks * 32 + (lane >> 4) * 8;
  union { u16 u[8]; uint4 v; } o;
#pragma unroll
  for (int j = 0; j < 8; ++j) o.u[j] = f2bf(src[(size_t)(kb + j) * 256 + col]);
  *(uint4*)(dst + (size_t)lt * 8) = o.v;
}

// ---------------------------------------------------------------------------
// CSR build: histogram -> exclusive scan -> scatter (counting sort by cell).
// ---------------------------------------------------------------------------
__global__ __launch_bounds__(256) void k_hist(const int* __restrict__ cells,
                                              int* __restrict__ counts, int E) {
  int e = blockIdx.x * 256 + threadIdx.x;
  if (e < E) atomicAdd(&counts[cells[e]], 1);
}

__global__ __launch_bounds__(1024) void k_scan(const int* __restrict__ counts,
                                               int* __restrict__ offs,
                                               int* __restrict__ cursor, int M) {
  __shared__ int wsum[16];
  __shared__ int cbase;
  const int tid = threadIdx.x;
  const int lane = tid & 63, wid = tid >> 6;
  if (tid == 0) cbase = 0;
  __syncthreads();
  const int nch = (M + 1023) >> 10;
  for (int ch = 0; ch < nch; ++ch) {
    int i = (ch << 10) + tid;
    int v = (i < M) ? counts[i] : 0;
    int x = v;
#pragma unroll
    for (int s = 1; s < 64; s <<= 1) {
      int y = __shfl_up(x, s);
      if (lane >= s) x += y;
    }
    if (lane == 63) wsum[wid] = x;
    __syncthreads();
    int wpre = 0;
    for (int w = 0; w < wid; ++w) wpre += wsum[w];
    int base = cbase;
    if (i < M) { int e = base + wpre + x - v; offs[i] = e; cursor[i] = e; }
    __syncthreads();
    if (tid == 1023) cbase = base + wpre + x;
    __syncthreads();
  }
  if (threadIdx.x == 0) offs[M] = cbase;
}

__global__ __launch_bounds__(256) void k_scatter(const int* __restrict__ cells,
                                                 const int* __restrict__ nodes,
                                                 int* __restrict__ cursor,
                                                 int* __restrict__ sorted, int E) {
  int e = blockIdx.x * 256 + threadIdx.x;
  if (e < E) {
    int c = cells[e];
    int p = atomicAdd(&cursor[c], 1);
    sorted[p] = nodes[e];
  }
}

// ---------------------------------------------------------------------------
// k_phi: H = relu(relu(X@W1+b1)@W2+b2) for all N nodes, output bf16.
// 4 waves/block, 16 rows/wave (16x16x32 bf16 MFMA, 16 n-tiles over 256 cols).
// Per-wave private 8KB LDS region holds inter-layer activations, XOR-swizzled
// (byte ^= (row&15)<<4 within the 512B row) so layer-2 ds_read_b128 A-fragment
// reads are bank-conflict-free.
// ---------------------------------------------------------------------------
__global__ __launch_bounds__(256) void k_phi(
    const float* __restrict__ X,
    const u16* __restrict__ W1s, const float* __restrict__ b1,
    const u16* __restrict__ W2s, const float* __restrict__ b2,
    u16* __restrict__ H, int N) {
  __shared__ __align__(16) u16 sbuf[4][4096];  // 4 waves x 16 rows x 256 bf16
  const int tid = threadIdx.x, lane = tid & 63, wid = tid >> 6;
  const int g = lane >> 4, r16 = lane & 15;
  const int rbase = blockIdx.x * 64 + wid * 16;
  int arow = rbase + r16;
  int arowc = arow < N ? arow : N - 1;
  u16* myl = &sbuf[wid][0];

  f32x4 acc[16];
#pragma unroll
  for (int nt = 0; nt < 16; ++nt) acc[nt] = (f32x4){0.f, 0.f, 0.f, 0.f};

  const float* xp = X + (size_t)arowc * 384 + g * 8;
  const u16* w1p = W1s + (size_t)lane * 8;
#pragma unroll
  for (int ks = 0; ks < 12; ++ks) {
    f32x4 a0 = *(const f32x4*)(xp + ks * 32);
    f32x4 a1 = *(const f32x4*)(xp + ks * 32 + 4);
    bf16x8 af;
#pragma unroll
    for (int j = 0; j < 4; ++j) { af[j] = (__bf16)a0[j]; af[4 + j] = (__bf16)a1[j]; }
#pragma unroll
    for (int nt = 0; nt < 16; ++nt) {
      bf16x8 bf = *(const bf16x8*)(w1p + (size_t)(ks * 16 + nt) * 512);
      acc[nt] = __builtin_amdgcn_mfma_f32_16x16x32_bf16(af, bf, acc[nt], 0, 0, 0);
    }
  }
  // bias + relu -> LDS (bf16, swizzled). C/D layout: col=lane&15, row=(lane>>4)*4+reg.
#pragma unroll
  for (int nt = 0; nt < 16; ++nt) {
    int col = nt * 16 + r16;
    float bb = b1[col];
#pragma unroll
    for (int rr = 0; rr < 4; ++rr) {
      int row = g * 4 + rr;
      float v = fmaxf(acc[nt][rr] + bb, 0.f);
      int ci = ((col * 2) ^ ((row & 15) << 4)) >> 1;
      myl[row * 256 + ci] = f2bf(v);
    }
  }
  asm volatile("s_waitcnt lgkmcnt(0)" ::: "memory");

  // layer 2: A from LDS, B from W2s
  f32x4 acc2[16];
#pragma unroll
  for (int nt = 0; nt < 16; ++nt) acc2[nt] = (f32x4){0.f, 0.f, 0.f, 0.f};
  const u16* w2p = W2s + (size_t)lane * 8;
#pragma unroll
  for (int ks = 0; ks < 8; ++ks) {
    int row = r16;
    int cb = (ks * 64 + g * 16) ^ ((row & 15) << 4);
    bf16x8 af = *(const bf16x8*)(myl + row * 256 + (cb >> 1));
#pragma unroll
    for (int nt = 0; nt < 16; ++nt) {
      bf16x8 bf = *(const bf16x8*)(w2p + (size_t)(ks * 16 + nt) * 512);
      acc2[nt] = __builtin_amdgcn_mfma_f32_16x16x32_bf16(af, bf, acc2[nt], 0, 0, 0);
    }
  }
  asm volatile("s_waitcnt lgkmcnt(0)" ::: "memory");

  // bias2 + relu -> LDS (reuse region), then coalesced copy to H
#pragma unroll
  for (int nt = 0; nt < 16; ++nt) {
    int col = nt * 16 + r16;
    float bb = b2[col];
#pragma unroll
    for (int rr = 0; rr < 4; ++rr) {
      int row = g * 4 + rr;
      float v = fmaxf(acc2[nt][rr] + bb, 0.f);
      int ci = ((col * 2) ^ ((row & 15) << 4)) >> 1;
      myl[row * 256 + ci] = f2bf(v);
    }
  }
  asm volatile("s_waitcnt lgkmcnt(0)" ::: "memory");
#pragma unroll
  for (int i = 0; i < 8; ++i) {
    int f = i * 1024 + lane * 16;  // byte offset within the wave's 8KB tile
    int row = f >> 9;
    int inner = f & 511;
    int sw = inner ^ ((row & 15) << 4);
    uint4 d = *(const uint4*)(myl + row * 256 + (sw >> 1));
    int grow = rbase + row;
    if (grow < N) *(uint4*)(H + (size_t)grow * 256 + (inner >> 1)) = d;
  }
}

// ---------------------------------------------------------------------------
// k_cellsum: one wave per cell; sum bf16 H rows (fp32 acc) over the cell's
// sorted edge list; write bf16 cell_sums row.
// ---------------------------------------------------------------------------
__global__ __launch_bounds__(256) void k_cellsum(
    const u16* __restrict__ H, const int* __restrict__ sorted,
    const int* __restrict__ offs, u16* __restrict__ CS, int M) {
  const int lane = threadIdx.x & 63, wid = threadIdx.x >> 6;
  int c = blockIdx.x * 4 + wid;
  if (c >= M) return;
  int s = offs[c], e = offs[c + 1];
  float a0 = 0.f, a1 = 0.f, a2 = 0.f, a3 = 0.f;
  for (int i = s; i < e; ++i) {
    int node = sorted[i];
    ushort4 h = *(const ushort4*)(H + (size_t)node * 256 + lane * 4);
    a0 += bf2f(h.x); a1 += bf2f(h.y); a2 += bf2f(h.z); a3 += bf2f(h.w);
  }
  ushort4 o;
  o.x = f2bf(a0); o.y = f2bf(a1); o.z = f2bf(a2); o.w = f2bf(a3);
  *(ushort4*)(CS + (size_t)c * 256 + lane * 4) = o;
}

// ---------------------------------------------------------------------------
// k_rho: OUT = relu(relu(CS@R1+c1)@R2+c2)@R3+c3, fp32 output. Same structure
// as k_phi but 3 layers; layer-1 A-frags come straight from bf16 CS rows.
// ---------------------------------------------------------------------------
__global__ __launch_bounds__(256) void k_rho(
    const u16* __restrict__ CS,
    const u16* __restrict__ R1s, const float* __restrict__ c1,
    const u16* __restrict__ R2s, const float* __restrict__ c2,
    const u16* __restrict__ R3s, const float* __restrict__ c3,
    float* __restrict__ OUT, int M) {
  __shared__ __align__(16) u16 sbuf[4][4096];
  const int tid = threadIdx.x, lane = tid & 63, wid = tid >> 6;
  const int g = lane >> 4, r16 = lane & 15;
  const int rbase = blockIdx.x * 64 + wid * 16;
  int arow = rbase + r16;
  int arowc = arow < M ? arow : M - 1;
  u16* myl = &sbuf[wid][0];

  // layer 1
  f32x4 acc[16];
#pragma unroll
  for (int nt = 0; nt < 16; ++nt) acc[nt] = (f32x4){0.f, 0.f, 0.f, 0.f};
  const u16* cp = CS + (size_t)arowc * 256 + g * 8;
  const u16* w1p = R1s + (size_t)lane * 8;
#pragma unroll
  for (int ks = 0; ks < 8; ++ks) {
    bf16x8 af = *(const bf16x8*)(cp + ks * 32);
#pragma unroll
    for (int nt = 0; nt < 16; ++nt) {
      bf16x8 bf = *(const bf16x8*)(w1p + (size_t)(ks * 16 + nt) * 512);
      acc[nt] = __builtin_amdgcn_mfma_f32_16x16x32_bf16(af, bf, acc[nt], 0, 0, 0);
    }
  }
#pragma unroll
  for (int nt = 0; nt < 16; ++nt) {
    int col = nt * 16 + r16;
    float bb = c1[col];
#pragma unroll
    for (int rr = 0; rr < 4; ++rr) {
      int row = g * 4 + rr;
      float v = fmaxf(acc[nt][rr] + bb, 0.f);
      int ci = ((col * 2) ^ ((row & 15) << 4)) >> 1;
      myl[row * 256 + ci] = f2bf(v);
    }
  }
  asm volatile("s_waitcnt lgkmcnt(0)" ::: "memory");

  // layer 2
  f32x4 acc2[16];
#pragma unroll
  for (int nt = 0; nt < 16; ++nt) acc2[nt] = (f32x4){0.f, 0.f, 0.f, 0.f};
  const u16* w2p = R2s + (size_t)lane * 8;
#pragma unroll
  for (int ks = 0; ks < 8; ++ks) {
    int row = r16;
    int cb = (ks * 64 + g * 16) ^ ((row & 15) << 4);
    bf16x8 af = *(const bf16x8*)(myl + row * 256 + (cb >> 1));
#pragma unroll
    for (int nt = 0; nt < 16; ++nt) {
      bf16x8 bf = *(const bf16x8*)(w2p + (size_t)(ks * 16 + nt) * 512);
      acc2[nt] = __builtin_amdgcn_mfma_f32_16x16x32_bf16(af, bf, acc2[nt], 0, 0, 0);
    }
  }
  asm volatile("s_waitcnt lgkmcnt(0)" ::: "memory");
#pragma unroll
  for (int nt = 0; nt < 16; ++nt) {
    int col = nt * 16 + r16;
    float bb = c2[col];
#pragma unroll
    for (int rr = 0; rr < 4; ++rr) {
      int row = g * 4 + rr;
      float v = fmaxf(acc2[nt][rr] + bb, 0.f);
      int ci = ((col * 2) ^ ((row & 15) << 4)) >> 1;
      myl[row * 256 + ci] = f2bf(v);
    }
  }
  asm volatile("s_waitcnt lgkmcnt(0)" ::: "memory");

  // layer 3 (no relu), direct fp32 stores
  f32x4 acc3[16];
#pragma unroll
  for (int nt = 0; nt < 16; ++nt) acc3[nt] = (f32x4){0.f, 0.f, 0.f, 0.f};
  const u16* w3p = R3s + (size_t)lane * 8;
#pragma unroll
  for (int ks = 0; ks < 8; ++ks) {
    int row = r16;
    int cb = (ks * 64 + g * 16) ^ ((row & 15) << 4);
    bf16x8 af = *(const bf16x8*)(myl + row * 256 + (cb >> 1));
#pragma unroll
    for (int nt = 0; nt < 16; ++nt) {
      bf16x8 bf = *(const bf16x8*)(w3p + (size_t)(ks * 16 + nt) * 512);
      acc3[nt] = __builtin_amdgcn_mfma_f32_16x16x32_bf16(af, bf, acc3[nt], 0, 0, 0);
    }
  }
#pragma unroll
  for (int nt = 0; nt < 16; ++nt) {
    int col = nt * 16 + r16;
    float bb = c3[col];
#pragma unroll
    for (int rr = 0; rr < 4; ++rr) {
      int row = g * 4 + rr;
      int grow = rbase + row;
      if (grow < M) OUT[(size_t)grow * 256 + col] = acc3[nt][rr] + bb;
    }
  }
}

// ---------------------------------------------------------------------------
extern "C" void kernel_launch(void* const* d_in, const int* in_sizes, int n_in,
                              void* d_out, int out_size, void* d_ws, size_t ws_size,
                              hipStream_t stream) {
  const float* X    = (const float*)d_in[0];
  const int* nodes  = (const int*)d_in[1];
  const int* cells  = (const int*)d_in[2];
  const float* W1   = (const float*)d_in[4];
  const float* b1   = (const float*)d_in[5];
  const float* W2   = (const float*)d_in[6];
  const float* b2   = (const float*)d_in[7];
  const float* R1   = (const float*)d_in[8];
  const float* c1   = (const float*)d_in[9];
  const float* R2   = (const float*)d_in[10];
  const float* c2   = (const float*)d_in[11];
  const float* R3   = (const float*)d_in[12];
  const float* c3   = (const float*)d_in[13];
  float* OUT = (float*)d_out;

  const int N = in_sizes[0] / 384;   // 100000
  const int E = in_sizes[1];         // 400000
  const int M = out_size / 256;      // 50000

  char* ws = (char*)d_ws;
  size_t off = 0;
  auto alloc = [&](size_t b) { size_t o = off; off += (b + 255) & ~(size_t)255; return o; };
  u16* W1s    = (u16*)(ws + alloc((size_t)12 * 16 * 64 * 8 * 2));
  u16* W2s    = (u16*)(ws + alloc((size_t)8 * 16 * 64 * 8 * 2));
  u16* R1s    = (u16*)(ws + alloc((size_t)8 * 16 * 64 * 8 * 2));
  u16* R2s    = (u16*)(ws + alloc((size_t)8 * 16 * 64 * 8 * 2));
  u16* R3s    = (u16*)(ws + alloc((size_t)8 * 16 * 64 * 8 * 2));
  u16* H      = (u16*)(ws + alloc((size_t)N * 256 * 2));
  u16* CS     = (u16*)(ws + alloc((size_t)M * 256 * 2));
  int* counts = (int*)(ws + alloc((size_t)M * 4));
  int* offs   = (int*)(ws + alloc((size_t)(M + 1) * 4));
  int* cursor = (int*)(ws + alloc((size_t)M * 4));
  int* sorted = (int*)(ws + alloc((size_t)E * 4));

  hipMemsetAsync(counts, 0, (size_t)M * 4, stream);
  k_prep<<<176, 256, 0, stream>>>(W1, W2, R1, R2, R3, W1s, W2s, R1s, R2s, R3s);
  k_hist<<<(E + 255) / 256, 256, 0, stream>>>(cells, counts, E);
  k_scan<<<1, 1024, 0, stream>>>(counts, offs, cursor, M);
  k_scatter<<<(E + 255) / 256, 256, 0, stream>>>(cells, nodes, cursor, sorted, E);
  k_phi<<<(N + 63) / 64, 256, 0, stream>>>(X, W1s, b1, W2s, b2, H, N);
  k_cellsum<<<(M + 3) / 4, 256, 0, stream>>>(H, sorted, offs, CS, M);
  k_rho<<<(M + 63) / 64, 256, 0, stream>>>(CS, R1s, c1, R2s, c2, R3s, c3, OUT, M);
}

// Round 2
// 232.562 us; speedup vs baseline: 2.1621x; 2.1621x over previous
//
#include <hip/hip_runtime.h>

typedef unsigned short u16;
typedef __bf16 bf16x8 __attribute__((ext_vector_type(8)));
typedef float f32x4 __attribute__((ext_vector_type(4)));

__device__ __forceinline__ u16 f2bf(float f) {
  unsigned int u = __builtin_bit_cast(unsigned int, f);
  u += 0x7fffu + ((u >> 16) & 1u);
  return (u16)(u >> 16);
}
__device__ __forceinline__ float bf2f(u16 h) {
  unsigned int u = ((unsigned int)h) << 16;
  return __builtin_bit_cast(float, u);
}

// ---------------------------------------------------------------------------
// k_prep: fp32 weights -> bf16 MFMA B-fragment order.
// Fragment (ks, nt, lane): 8 elems W[ks*32 + (lane>>4)*8 + j][nt*16 + (lane&15)]
// at dst[((ks*16+nt)*64 + lane)*8 + j].
// ---------------------------------------------------------------------------
__global__ __launch_bounds__(256) void k_prep(
    const float* __restrict__ W1, const float* __restrict__ W2,
    const float* __restrict__ R1, const float* __restrict__ R2, const float* __restrict__ R3,
    u16* __restrict__ W1s, u16* __restrict__ W2s,
    u16* __restrict__ R1s, u16* __restrict__ R2s, u16* __restrict__ R3s) {
  int t = blockIdx.x * 256 + threadIdx.x;
  const float* src; u16* dst; int lt;
  if (t < 12288) { src = W1; dst = W1s; lt = t; }
  else {
    int u = t - 12288;
    int m = u >> 13;
    lt = u & 8191;
    if (m == 0)      { src = W2; dst = W2s; }
    else if (m == 1) { src = R1; dst = R1s; }
    else if (m == 2) { src = R2; dst = R2s; }
    else if (m == 3) { src = R3; dst = R3s; }
    else return;
  }
  int lane = lt & 63;
  int nt = (lt >> 6) & 15;
  int ks = lt >> 10;
  int col = nt * 16 + (lane & 15);
  int kb = ks * 32 + (lane >> 4) * 8;
  union { u16 u[8]; uint4 v; } o;
#pragma unroll
  for (int j = 0; j < 8; ++j) o.u[j] = f2bf(src[(size_t)(kb + j) * 256 + col]);
  *(uint4*)(dst + (size_t)lt * 8) = o.v;
}

// ---------------------------------------------------------------------------
// CSR build: histogram -> 3-stage multi-block exclusive scan -> scatter.
// ---------------------------------------------------------------------------
__global__ __launch_bounds__(256) void k_hist(const int* __restrict__ cells,
                                              int* __restrict__ counts, int E) {
  int e = blockIdx.x * 256 + threadIdx.x;
  if (e < E) atomicAdd(&counts[cells[e]], 1);
}

__global__ __launch_bounds__(256) void k_scan1(const int* __restrict__ counts,
                                               int* __restrict__ offs,
                                               int* __restrict__ bsum, int M) {
  __shared__ int ws[4];
  int tid = threadIdx.x, lane = tid & 63, wid = tid >> 6;
  int i = blockIdx.x * 256 + tid;
  int v = (i < M) ? counts[i] : 0;
  int x = v;
#pragma unroll
  for (int s = 1; s < 64; s <<= 1) { int y = __shfl_up(x, s); if (lane >= s) x += y; }
  if (lane == 63) ws[wid] = x;
  __syncthreads();
  int pre = 0;
#pragma unroll
  for (int w = 0; w < 4; ++w) if (w < wid) pre += ws[w];
  if (i < M) offs[i] = pre + x - v;
  if (tid == 255) bsum[blockIdx.x] = pre + x;
}

__global__ __launch_bounds__(256) void k_scan2(int* __restrict__ bsum, int nb) {
  __shared__ int ws[4];
  int tid = threadIdx.x, lane = tid & 63, wid = tid >> 6;
  int v = (tid < nb) ? bsum[tid] : 0;
  int x = v;
#pragma unroll
  for (int s = 1; s < 64; s <<= 1) { int y = __shfl_up(x, s); if (lane >= s) x += y; }
  if (lane == 63) ws[wid] = x;
  __syncthreads();
  int pre = 0;
#pragma unroll
  for (int w = 0; w < 4; ++w) if (w < wid) pre += ws[w];
  if (tid < nb) bsum[tid] = pre + x - v;
}

__global__ __launch_bounds__(256) void k_scan3(int* __restrict__ offs,
                                               const int* __restrict__ bsum,
                                               int* __restrict__ cursor, int M, int E) {
  int i = blockIdx.x * 256 + threadIdx.x;
  if (i < M) { int o = offs[i] + bsum[blockIdx.x]; offs[i] = o; cursor[i] = o; }
  if (i == M) offs[M] = E;
}

__global__ __launch_bounds__(256) void k_scatter(const int* __restrict__ cells,
                                                 const int* __restrict__ nodes,
                                                 int* __restrict__ cursor,
                                                 int* __restrict__ sorted, int E) {
  int e = blockIdx.x * 256 + threadIdx.x;
  if (e < E) {
    int c = cells[e];
    int p = atomicAdd(&cursor[c], 1);
    sorted[p] = nodes[e];
  }
}

// ---------------------------------------------------------------------------
// k_phi: H = relu(relu(X@W1+b1)@W2+b2), col-split structure.
// Block = 4 waves x 64 rows. Wave w owns cols [w*64, w*64+64).
// A staged in flat LDS [64][256] bf16, u16-idx = row*256 + (kk ^ ((row&15)<<3))
// (round-0 swizzle family, measured 0 bank conflicts). Each B-fragment load
// feeds 4 MFMAs (4 m-tiles). Layer 1 (K=384) staged in two K-phases to fit
// 32 KB stage + 32 KB hbuf = 64 KB LDS.
// ---------------------------------------------------------------------------
__global__ __launch_bounds__(256, 2) void k_phi(
    const float* __restrict__ X,
    const u16* __restrict__ W1s, const float* __restrict__ b1,
    const u16* __restrict__ W2s, const float* __restrict__ b2,
    u16* __restrict__ H, int N) {
  __shared__ __align__(16) u16 stage[64 * 256];
  __shared__ __align__(16) u16 hbuf[64 * 256];
  const int tid = threadIdx.x, lane = tid & 63, wid = tid >> 6;
  const int g = lane >> 4, r16 = lane & 15;
  const int rbase = blockIdx.x * 64;

  f32x4 acc[4][4];
#pragma unroll
  for (int m = 0; m < 4; ++m)
#pragma unroll
    for (int n = 0; n < 4; ++n) acc[m][n] = (f32x4){0.f, 0.f, 0.f, 0.f};

#pragma unroll
  for (int ph = 0; ph < 2; ++ph) {
    if (ph) __syncthreads();  // all waves done with phase-0 A before overwrite
    if (ph == 0) {
#pragma unroll
      for (int it = 0; it < 16; ++it) {
        int u = it * 256 + tid;
        int row = u >> 6, c4 = u & 63;
        int crow = rbase + row; crow = crow < N ? crow : N - 1;
        f32x4 v = *(const f32x4*)(X + (size_t)crow * 384 + c4 * 4);
        uint2 pk;
        pk.x = (unsigned int)f2bf(v[0]) | ((unsigned int)f2bf(v[1]) << 16);
        pk.y = (unsigned int)f2bf(v[2]) | ((unsigned int)f2bf(v[3]) << 16);
        *(uint2*)(stage + row * 256 + ((c4 * 4) ^ ((row & 15) << 3))) = pk;
      }
    } else {
#pragma unroll
      for (int it = 0; it < 8; ++it) {
        int u = it * 256 + tid;
        int row = u >> 5, c4 = u & 31;
        int crow = rbase + row; crow = crow < N ? crow : N - 1;
        f32x4 v = *(const f32x4*)(X + (size_t)crow * 384 + 256 + c4 * 4);
        uint2 pk;
        pk.x = (unsigned int)f2bf(v[0]) | ((unsigned int)f2bf(v[1]) << 16);
        pk.y = (unsigned int)f2bf(v[2]) | ((unsigned int)f2bf(v[3]) << 16);
        *(uint2*)(stage + row * 256 + ((c4 * 4) ^ ((row & 15) << 3))) = pk;
      }
    }
    __syncthreads();
    const int nks = ph ? 4 : 8;
    const int ksg0 = ph ? 8 : 0;
#pragma unroll
    for (int ksl = 0; ksl < nks; ++ksl) {
      int ks = ksg0 + ksl;
      bf16x8 bfr[4];
#pragma unroll
      for (int n = 0; n < 4; ++n)
        bfr[n] = *(const bf16x8*)(W1s + ((size_t)(ks * 16 + wid * 4 + n) * 64 + lane) * 8);
#pragma unroll
      for (int m = 0; m < 4; ++m) {
        int row = m * 16 + r16;
        bf16x8 af = *(const bf16x8*)(stage + row * 256 + ((ksl * 32 + g * 8) ^ (r16 << 3)));
#pragma unroll
        for (int n = 0; n < 4; ++n)
          acc[m][n] = __builtin_amdgcn_mfma_f32_16x16x32_bf16(af, bfr[n], acc[m][n], 0, 0, 0);
      }
    }
  }

  // h1 = relu(acc + b1) -> hbuf
  float bias1[4];
#pragma unroll
  for (int n = 0; n < 4; ++n) bias1[n] = b1[wid * 64 + n * 16 + r16];
#pragma unroll
  for (int m = 0; m < 4; ++m)
#pragma unroll
    for (int n = 0; n < 4; ++n)
#pragma unroll
      for (int rr = 0; rr < 4; ++rr) {
        int row = m * 16 + g * 4 + rr;
        int col = wid * 64 + n * 16 + r16;
        float v = fmaxf(acc[m][n][rr] + bias1[n], 0.f);
        hbuf[row * 256 + (col ^ ((row & 15) << 3))] = f2bf(v);
      }
  __syncthreads();

  // layer 2
  f32x4 acc2[4][4];
#pragma unroll
  for (int m = 0; m < 4; ++m)
#pragma unroll
    for (int n = 0; n < 4; ++n) acc2[m][n] = (f32x4){0.f, 0.f, 0.f, 0.f};
#pragma unroll
  for (int ks = 0; ks < 8; ++ks) {
    bf16x8 bfr[4];
#pragma unroll
    for (int n = 0; n < 4; ++n)
      bfr[n] = *(const bf16x8*)(W2s + ((size_t)(ks * 16 + wid * 4 + n) * 64 + lane) * 8);
#pragma unroll
    for (int m = 0; m < 4; ++m) {
      int row = m * 16 + r16;
      bf16x8 af = *(const bf16x8*)(hbuf + row * 256 + ((ks * 32 + g * 8) ^ (r16 << 3)));
#pragma unroll
      for (int n = 0; n < 4; ++n)
        acc2[m][n] = __builtin_amdgcn_mfma_f32_16x16x32_bf16(af, bfr[n], acc2[m][n], 0, 0, 0);
    }
  }

  // h2 = relu(acc2 + b2) -> stage (safe: all waves past layer-1 via prior barrier)
  float bias2[4];
#pragma unroll
  for (int n = 0; n < 4; ++n) bias2[n] = b2[wid * 64 + n * 16 + r16];
#pragma unroll
  for (int m = 0; m < 4; ++m)
#pragma unroll
    for (int n = 0; n < 4; ++n)
#pragma unroll
      for (int rr = 0; rr < 4; ++rr) {
        int row = m * 16 + g * 4 + rr;
        int col = wid * 64 + n * 16 + r16;
        float v = fmaxf(acc2[m][n][rr] + bias2[n], 0.f);
        stage[row * 256 + (col ^ ((row & 15) << 3))] = f2bf(v);
      }
  __syncthreads();

  // coalesced copy out
#pragma unroll
  for (int it = 0; it < 8; ++it) {
    int u = it * 256 + tid;
    int row = u >> 5, k8 = u & 31;
    uint4 d = *(const uint4*)(stage + row * 256 + ((k8 * 8) ^ ((row & 15) << 3)));
    int grow = rbase + row;
    if (grow < N) *(uint4*)(H + (size_t)grow * 256 + k8 * 8) = d;
  }
}

// ---------------------------------------------------------------------------
// k_cellsum: one wave per cell; fp32-accumulate bf16 H rows over sorted edges.
// ---------------------------------------------------------------------------
__global__ __launch_bounds__(256) void k_cellsum(
    const u16* __restrict__ H, const int* __restrict__ sorted,
    const int* __restrict__ offs, u16* __restrict__ CS, int M) {
  const int lane = threadIdx.x & 63, wid = threadIdx.x >> 6;
  int c = blockIdx.x * 4 + wid;
  if (c >= M) return;
  int s = offs[c], e = offs[c + 1];
  float a0 = 0.f, a1 = 0.f, a2 = 0.f, a3 = 0.f;
  for (int i = s; i < e; ++i) {
    int node = sorted[i];
    ushort4 h = *(const ushort4*)(H + (size_t)node * 256 + lane * 4);
    a0 += bf2f(h.x); a1 += bf2f(h.y); a2 += bf2f(h.z); a3 += bf2f(h.w);
  }
  ushort4 o;
  o.x = f2bf(a0); o.y = f2bf(a1); o.z = f2bf(a2); o.w = f2bf(a3);
  *(ushort4*)(CS + (size_t)c * 256 + lane * 4) = o;
}

// ---------------------------------------------------------------------------
// k_rho: OUT = relu(relu(CS@R1+c1)@R2+c2)@R3+c3, same col-split structure,
// 3 layers, fp32 direct global stores (64B row segments).
// ---------------------------------------------------------------------------
__global__ __launch_bounds__(256, 2) void k_rho(
    const u16* __restrict__ CS,
    const u16* __restrict__ R1s, const float* __restrict__ c1,
    const u16* __restrict__ R2s, const float* __restrict__ c2,
    const u16* __restrict__ R3s, const float* __restrict__ c3,
    float* __restrict__ OUT, int M) {
  __shared__ __align__(16) u16 stage[64 * 256];
  __shared__ __align__(16) u16 hbuf[64 * 256];
  const int tid = threadIdx.x, lane = tid & 63, wid = tid >> 6;
  const int g = lane >> 4, r16 = lane & 15;
  const int rbase = blockIdx.x * 64;

  // stage CS tile (already bf16)
#pragma unroll
  for (int it = 0; it < 8; ++it) {
    int u = it * 256 + tid;
    int row = u >> 5, k8 = u & 31;
    int crow = rbase + row; crow = crow < M ? crow : M - 1;
    uint4 d = *(const uint4*)(CS + (size_t)crow * 256 + k8 * 8);
    *(uint4*)(stage + row * 256 + ((k8 * 8) ^ ((row & 15) << 3))) = d;
  }
  __syncthreads();

  // layer 1
  f32x4 acc[4][4];
#pragma unroll
  for (int m = 0; m < 4; ++m)
#pragma unroll
    for (int n = 0; n < 4; ++n) acc[m][n] = (f32x4){0.f, 0.f, 0.f, 0.f};
#pragma unroll
  for (int ks = 0; ks < 8; ++ks) {
    bf16x8 bfr[4];
#pragma unroll
    for (int n = 0; n < 4; ++n)
      bfr[n] = *(const bf16x8*)(R1s + ((size_t)(ks * 16 + wid * 4 + n) * 64 + lane) * 8);
#pragma unroll
    for (int m = 0; m < 4; ++m) {
      int row = m * 16 + r16;
      bf16x8 af = *(const bf16x8*)(stage + row * 256 + ((ks * 32 + g * 8) ^ (r16 << 3)));
#pragma unroll
      for (int n = 0; n < 4; ++n)
        acc[m][n] = __builtin_amdgcn_mfma_f32_16x16x32_bf16(af, bfr[n], acc[m][n], 0, 0, 0);
    }
  }
  float bias1[4];
#pragma unroll
  for (int n = 0; n < 4; ++n) bias1[n] = c1[wid * 64 + n * 16 + r16];
#pragma unroll
  for (int m = 0; m < 4; ++m)
#pragma unroll
    for (int n = 0; n < 4; ++n)
#pragma unroll
      for (int rr = 0; rr < 4; ++rr) {
        int row = m * 16 + g * 4 + rr;
        int col = wid * 64 + n * 16 + r16;
        float v = fmaxf(acc[m][n][rr] + bias1[n], 0.f);
        hbuf[row * 256 + (col ^ ((row & 15) << 3))] = f2bf(v);
      }
  __syncthreads();

  // layer 2
  f32x4 acc2[4][4];
#pragma unroll
  for (int m = 0; m < 4; ++m)
#pragma unroll
    for (int n = 0; n < 4; ++n) acc2[m][n] = (f32x4){0.f, 0.f, 0.f, 0.f};
#pragma unroll
  for (int ks = 0; ks < 8; ++ks) {
    bf16x8 bfr[4];
#pragma unroll
    for (int n = 0; n < 4; ++n)
      bfr[n] = *(const bf16x8*)(R2s + ((size_t)(ks * 16 + wid * 4 + n) * 64 + lane) * 8);
#pragma unroll
    for (int m = 0; m < 4; ++m) {
      int row = m * 16 + r16;
      bf16x8 af = *(const bf16x8*)(hbuf + row * 256 + ((ks * 32 + g * 8) ^ (r16 << 3)));
#pragma unroll
      for (int n = 0; n < 4; ++n)
        acc2[m][n] = __builtin_amdgcn_mfma_f32_16x16x32_bf16(af, bfr[n], acc2[m][n], 0, 0, 0);
    }
  }
  float bias2[4];
#pragma unroll
  for (int n = 0; n < 4; ++n) bias2[n] = c2[wid * 64 + n * 16 + r16];
#pragma unroll
  for (int m = 0; m < 4; ++m)
#pragma unroll
    for (int n = 0; n < 4; ++n)
#pragma unroll
      for (int rr = 0; rr < 4; ++rr) {
        int row = m * 16 + g * 4 + rr;
        int col = wid * 64 + n * 16 + r16;
        float v = fmaxf(acc2[m][n][rr] + bias2[n], 0.f);
        stage[row * 256 + (col ^ ((row & 15) << 3))] = f2bf(v);
      }
  __syncthreads();

  // layer 3 (no relu), direct fp32 stores
  f32x4 acc3[4][4];
#pragma unroll
  for (int m = 0; m < 4; ++m)
#pragma unroll
    for (int n = 0; n < 4; ++n) acc3[m][n] = (f32x4){0.f, 0.f, 0.f, 0.f};
#pragma unroll
  for (int ks = 0; ks < 8; ++ks) {
    bf16x8 bfr[4];
#pragma unroll
    for (int n = 0; n < 4; ++n)
      bfr[n] = *(const bf16x8*)(R3s + ((size_t)(ks * 16 + wid * 4 + n) * 64 + lane) * 8);
#pragma unroll
    for (int m = 0; m < 4; ++m) {
      int row = m * 16 + r16;
      bf16x8 af = *(const bf16x8*)(stage + row * 256 + ((ks * 32 + g * 8) ^ (r16 << 3)));
#pragma unroll
      for (int n = 0; n < 4; ++n)
        acc3[m][n] = __builtin_amdgcn_mfma_f32_16x16x32_bf16(af, bfr[n], acc3[m][n], 0, 0, 0);
    }
  }
#pragma unroll
  for (int n = 0; n < 4; ++n) {
    float bias = c3[wid * 64 + n * 16 + r16];
#pragma unroll
    for (int m = 0; m < 4; ++m)
#pragma unroll
      for (int rr = 0; rr < 4; ++rr) {
        int grow = rbase + m * 16 + g * 4 + rr;
        if (grow < M) OUT[(size_t)grow * 256 + wid * 64 + n * 16 + r16] = acc3[m][n][rr] + bias;
      }
  }
}

// ---------------------------------------------------------------------------
extern "C" void kernel_launch(void* const* d_in, const int* in_sizes, int n_in,
                              void* d_out, int out_size, void* d_ws, size_t ws_size,
                              hipStream_t stream) {
  const float* X    = (const float*)d_in[0];
  const int* nodes  = (const int*)d_in[1];
  const int* cells  = (const int*)d_in[2];
  const float* W1   = (const float*)d_in[4];
  const float* b1   = (const float*)d_in[5];
  const float* W2   = (const float*)d_in[6];
  const float* b2   = (const float*)d_in[7];
  const float* R1   = (const float*)d_in[8];
  const float* c1   = (const float*)d_in[9];
  const float* R2   = (const float*)d_in[10];
  const float* c2   = (const float*)d_in[11];
  const float* R3   = (const float*)d_in[12];
  const float* c3   = (const float*)d_in[13];
  float* OUT = (float*)d_out;

  const int N = in_sizes[0] / 384;   // 100000
  const int E = in_sizes[1];         // 400000
  const int M = out_size / 256;      // 50000

  char* ws = (char*)d_ws;
  size_t off = 0;
  auto alloc = [&](size_t b) { size_t o = off; off += (b + 255) & ~(size_t)255; return o; };
  u16* W1s    = (u16*)(ws + alloc((size_t)12 * 16 * 64 * 8 * 2));
  u16* W2s    = (u16*)(ws + alloc((size_t)8 * 16 * 64 * 8 * 2));
  u16* R1s    = (u16*)(ws + alloc((size_t)8 * 16 * 64 * 8 * 2));
  u16* R2s    = (u16*)(ws + alloc((size_t)8 * 16 * 64 * 8 * 2));
  u16* R3s    = (u16*)(ws + alloc((size_t)8 * 16 * 64 * 8 * 2));
  u16* H      = (u16*)(ws + alloc((size_t)N * 256 * 2));
  u16* CS     = (u16*)(ws + alloc((size_t)M * 256 * 2));
  int* counts = (int*)(ws + alloc((size_t)M * 4));
  int* offs   = (int*)(ws + alloc((size_t)(M + 1) * 4));
  int* cursor = (int*)(ws + alloc((size_t)M * 4));
  int* sorted = (int*)(ws + alloc((size_t)E * 4));
  int* bsum   = (int*)(ws + alloc((size_t)256 * 4));

  const int NB = (M + 255) / 256;

  hipMemsetAsync(counts, 0, (size_t)M * 4, stream);
  k_prep<<<176, 256, 0, stream>>>(W1, W2, R1, R2, R3, W1s, W2s, R1s, R2s, R3s);
  k_hist<<<(E + 255) / 256, 256, 0, stream>>>(cells, counts, E);
  k_scan1<<<NB, 256, 0, stream>>>(counts, offs, bsum, M);
  k_scan2<<<1, 256, 0, stream>>>(bsum, NB);
  k_scan3<<<(M + 256) / 256, 256, 0, stream>>>(offs, bsum, cursor, M, E);
  k_scatter<<<(E + 255) / 256, 256, 0, stream>>>(cells, nodes, cursor, sorted, E);
  k_phi<<<(N + 63) / 64, 256, 0, stream>>>(X, W1s, b1, W2s, b2, H, N);
  k_cellsum<<<(M + 3) / 4, 256, 0, stream>>>(H, sorted, offs, CS, M);
  k_rho<<<(M + 63) / 64, 256, 0, stream>>>(CS, R1s, c1, R2s, c2, R3s, c3, OUT, M);
}